// Round 1
// baseline (709.196 us; speedup 1.0000x reference)
//
#include <hip/hip_runtime.h>
#include <math.h>

#define N1 16384
#define N2 16384
#define BLOCK 256
#define PTS 4                         // pos1 points per thread
#define I_BLOCKS (N1 / (BLOCK * PTS)) // 16 blocks along pos1
#define MAX_SLICE_N 1024              // LDS capacity for a pos2 slice

// Stage 1: each block computes, for its 1024 pos1 points, the min squared
// distance against one pos2 slice (staged in LDS). Writes partial minima
// to ws[slice * N1 + i].
__global__ __launch_bounds__(BLOCK)
void nn_partial(const float2* __restrict__ pos1,
                const float2* __restrict__ pos2,
                float* __restrict__ partials,
                int slice_n) {
    __shared__ float2 sp[MAX_SLICE_N];
    const int ib = blockIdx.x;
    const int sl = blockIdx.y;
    const int t  = threadIdx.x;

    // cooperative load of this block's pos2 slice into LDS
    for (int j = t; j < slice_n; j += BLOCK) {
        sp[j] = pos2[sl * slice_n + j];
    }
    __syncthreads();

    const int i0 = ib * (BLOCK * PTS) + t;
    float x[PTS], y[PTS], m[PTS];
#pragma unroll
    for (int k = 0; k < PTS; ++k) {
        float2 p = pos1[i0 + k * BLOCK];
        x[k] = p.x;
        y[k] = p.y;
        m[k] = 3.4e38f;
    }

#pragma unroll 4
    for (int j = 0; j < slice_n; ++j) {
        float2 q = sp[j];   // same address across the wave -> LDS broadcast
#pragma unroll
        for (int k = 0; k < PTS; ++k) {
            float dx = x[k] - q.x;
            float dy = y[k] - q.y;
            float d2 = fmaf(dy, dy, dx * dx);
            m[k] = fminf(m[k], d2);
        }
    }

#pragma unroll
    for (int k = 0; k < PTS; ++k) {
        partials[(size_t)sl * N1 + i0 + k * BLOCK] = m[k];
    }
}

// Stage 2: single block. min over slices per point, sqrt, block-sum, mean.
__global__ __launch_bounds__(BLOCK)
void nn_reduce(const float* __restrict__ partials,
               float* __restrict__ out,
               int slices) {
    const int t = threadIdx.x;
    float sum = 0.f;
    for (int p = 0; p < N1 / BLOCK; ++p) {
        const int i = p * BLOCK + t;
        float m = 3.4e38f;
        for (int s = 0; s < slices; ++s) {
            m = fminf(m, partials[(size_t)s * N1 + i]);
        }
        sum += sqrtf(m);
    }
    // wave (64-lane) shuffle reduce
    for (int off = 32; off > 0; off >>= 1) {
        sum += __shfl_down(sum, off, 64);
    }
    __shared__ float wsum[BLOCK / 64];
    if ((t & 63) == 0) wsum[t >> 6] = sum;
    __syncthreads();
    if (t == 0) {
        float s = 0.f;
        for (int w = 0; w < BLOCK / 64; ++w) s += wsum[w];
        out[0] = s / (float)N1;
    }
}

extern "C" void kernel_launch(void* const* d_in, const int* in_sizes, int n_in,
                              void* d_out, int out_size, void* d_ws, size_t ws_size,
                              hipStream_t stream) {
    const float2* pos1 = (const float2*)d_in[0];
    const float2* pos2 = (const float2*)d_in[1];
    float* out = (float*)d_out;
    float* partials = (float*)d_ws;

    // 64 slices -> 4 MB workspace; degrade gracefully if ws is smaller.
    int slices = 64;
    while (slices > 1 && (size_t)slices * N1 * sizeof(float) > ws_size) slices >>= 1;
    // keep slice_n within LDS tile capacity
    while (N2 / slices > MAX_SLICE_N) slices <<= 1;
    const int slice_n = N2 / slices;

    dim3 grid(I_BLOCKS, slices);
    nn_partial<<<grid, BLOCK, 0, stream>>>(pos1, pos2, partials, slice_n);
    nn_reduce<<<1, BLOCK, 0, stream>>>(partials, out, slices);
}

// Round 2
// 87.414 us; speedup vs baseline: 8.1131x; 8.1131x over previous
//
#include <hip/hip_runtime.h>
#include <math.h>

#define N1 16384
#define N2 16384
#define BLOCK 256
#define PTS 8                          // pos1 points per thread (ILP + LDS amortization)
#define I_BLOCKS (N1 / (BLOCK * PTS))  // 8 blocks along pos1
#define MAX_SLICE_N 1024               // LDS capacity for a pos2 slice (float4)

// Stage 1: partial min over one pos2 slice of g(q) = -2 p.q + |q|^2
// (d^2 = |p|^2 + g(q); the |p|^2 shift is added in stage 2).
// LDS holds precomputed (-2qx, -2qy, |q|^2) per slice point -> inner loop is
// 2 FMA + 1 min per pair.
__global__ __launch_bounds__(BLOCK)
void nn_partial(const float2* __restrict__ pos1,
                const float2* __restrict__ pos2,
                float* __restrict__ partials,
                int slice_n) {
    __shared__ float4 sp[MAX_SLICE_N];
    const int ib = blockIdx.x;
    const int sl = blockIdx.y;
    const int t  = threadIdx.x;

    for (int j = t; j < slice_n; j += BLOCK) {
        float2 q = pos2[sl * slice_n + j];
        sp[j] = make_float4(-2.f * q.x, -2.f * q.y,
                            fmaf(q.x, q.x, q.y * q.y), 0.f);
    }
    __syncthreads();

    const int i0 = ib * (BLOCK * PTS) + t;
    float x[PTS], y[PTS], m[PTS];
#pragma unroll
    for (int k = 0; k < PTS; ++k) {
        float2 p = pos1[i0 + k * BLOCK];
        x[k] = p.x;
        y[k] = p.y;
        m[k] = 3.4e38f;
    }

#pragma unroll 2
    for (int j = 0; j < slice_n; ++j) {
        float4 q = sp[j];   // wave-uniform address -> LDS broadcast
#pragma unroll
        for (int k = 0; k < PTS; ++k) {
            float g = fmaf(x[k], q.x, fmaf(y[k], q.y, q.z));
            m[k] = fminf(m[k], g);
        }
    }

#pragma unroll
    for (int k = 0; k < PTS; ++k) {
        partials[(size_t)sl * N1 + i0 + k * BLOCK] = m[k];
    }
}

// Stage 2: 64 blocks; each thread owns one pos1 point: min over slices
// (coalesced), add |p|^2, sqrt, block-sum -> blocksums[blockIdx].
__global__ __launch_bounds__(BLOCK)
void nn_reduce(const float* __restrict__ partials,
               const float2* __restrict__ pos1,
               float* __restrict__ blocksums,
               int slices) {
    const int t = threadIdx.x;
    const int i = blockIdx.x * BLOCK + t;

    float m = 3.4e38f;
    for (int s = 0; s < slices; ++s) {
        m = fminf(m, partials[(size_t)s * N1 + i]);
    }
    float2 p = pos1[i];
    float d2 = fmaxf(fmaf(p.x, p.x, p.y * p.y) + m, 0.f);
    float sum = sqrtf(d2);

    for (int off = 32; off > 0; off >>= 1) {
        sum += __shfl_down(sum, off, 64);
    }
    __shared__ float wsum[BLOCK / 64];
    if ((t & 63) == 0) wsum[t >> 6] = sum;
    __syncthreads();
    if (t == 0) {
        float s = 0.f;
        for (int w = 0; w < BLOCK / 64; ++w) s += wsum[w];
        blocksums[blockIdx.x] = s;
    }
}

// Stage 3: one wave sums the 64 block sums and writes the mean.
__global__ __launch_bounds__(64)
void nn_final(const float* __restrict__ blocksums,
              float* __restrict__ out, int nblk) {
    const int t = threadIdx.x;
    float sum = (t < nblk) ? blocksums[t] : 0.f;
    for (int off = 32; off > 0; off >>= 1) {
        sum += __shfl_down(sum, off, 64);
    }
    if (t == 0) out[0] = sum / (float)N1;
}

extern "C" void kernel_launch(void* const* d_in, const int* in_sizes, int n_in,
                              void* d_out, int out_size, void* d_ws, size_t ws_size,
                              hipStream_t stream) {
    const float2* pos1 = (const float2*)d_in[0];
    const float2* pos2 = (const float2*)d_in[1];
    float* out = (float*)d_out;
    float* partials = (float*)d_ws;

    const int nblk2 = N1 / BLOCK;  // 64
    // 64 slices -> 4 MB partials + blocksums; degrade if ws is smaller.
    int slices = 64;
    while (slices > 1 &&
           (size_t)slices * N1 * sizeof(float) + nblk2 * sizeof(float) > ws_size)
        slices >>= 1;
    while (N2 / slices > MAX_SLICE_N) slices <<= 1;
    const int slice_n = N2 / slices;

    float* blocksums = partials + (size_t)slices * N1;

    dim3 grid1(I_BLOCKS, slices);
    nn_partial<<<grid1, BLOCK, 0, stream>>>(pos1, pos2, partials, slice_n);
    nn_reduce<<<nblk2, BLOCK, 0, stream>>>(partials, pos1, blocksums, slices);
    nn_final<<<1, 64, 0, stream>>>(blocksums, out, nblk2);
}